// Round 14
// baseline (165.546 us; speedup 1.0000x reference)
//
#include <hip/hip_runtime.h>

// ---------------- problem constants ----------------
#define NBLK   98304     // 8*3*64*64 total 8x8 blocks
#define NPB    12288     // blocks per batch (3*64*64)
#define HW     512
#define NUMBITS 4096
#define RANK0  29490     // floor(0.3*(NBLK-1)); sel <=> var > s[RANK0] (adjacent order stats)
#define STEGO_N 6291456  // 8*3*512*512
#define ELIG   111       // ceil(4096/37) blocks contain eligible coefficients
#define HISTB  512       // fixed bins over variance range [0, 0.25]
#define CAPB   4096      // per-bin bucket capacity (bin-b0 population ~500)
#define NWGS   96

typedef unsigned long long ull;

// ---------------- DCT matrix as compile-time constants ----------------
struct DTab { double d[8][8]; };

constexpr double CT_[9] = {
  1.0,
  0.98078528040323044913,
  0.92387953251128675613,
  0.83146961230254523708,
  0.70710678118654752440,
  0.55557023301960222474,
  0.38268343236508977173,
  0.19509032201612826785,
  0.0
};
constexpr double cospi16(int m){           // cos(pi*m/16), m >= 0
  int r = m % 32;
  return (r<=8) ? CT_[r] : (r<=16) ? -CT_[16-r] : (r<=24) ? -CT_[r-16] : CT_[32-r];
}
constexpr DTab make_dtab(){
  DTab t{};
  for(int k=0;k<8;k++) for(int n=0;n<8;n++){
    double s = (k==0) ? 0.35355339059327376220 : 0.5; // sqrt(1/8), sqrt(2/8)
    t.d[k][n] = s * cospi16((2*n+1)*k);
  }
  return t;
}
constexpr DTab DT = make_dtab();

constexpr ull make_fmask(){ // bit u*8+v set iff 3 <= u+v <= 8
  ull m = 0;
  for(int u=0;u<8;u++) for(int v=0;v<8;v++){
    int s=u+v; if(s>=3 && s<=8) m |= (1ULL << (u*8+v));
  }
  return m;
}
constexpr ull FMASK = make_fmask();  // 37 bits set

__device__ __forceinline__ int binof(double v){
  int b = (int)(v * 2048.0);                // HISTB/0.25 — fixed, deterministic
  if(b > HISTB-1) b = HISTB-1;
  return b;                                 // v >= 0 always
}

// one WAVE embeds one block (global selected-rank S2); lane l owns coeff (l>>3,l&7)
__device__ __forceinline__ void embed_one(const float* __restrict__ cover,
    const int* __restrict__ secret, float* __restrict__ out, int bi, int S2, int lane){
  int lr = lane>>3, lc = lane&7;
  int m = bi & 63, n = (bi>>6)&63, bc = bi>>12, bb = bi / NPB;
  const float* p  = cover + ((size_t)bc*HW + (size_t)n*8)*HW + (size_t)m*8;
  float*       po = out   + ((size_t)bc*HW + (size_t)n*8)*HW + (size_t)m*8;
  double x = (double)p[(size_t)lr*HW + lc];     // X[lr][lc]
  // stage1: T1[r][v] = sum_j X[r][j]*D[v][j]
  double t1 = 0.0;
#pragma unroll
  for(int j=0;j<8;j++) t1 += __shfl(x, lr*8+j) * DT.d[lc][j];
  // stage2: C[u][v] = sum_k D[u][k]*T1[k][v]
  double coef = 0.0;
#pragma unroll
  for(int k=0;k<8;k++) coef += DT.d[lr][k] * __shfl(t1, k*8+lc);
  // embedding
  bool sel = (FMASK>>lane)&1ULL;
  float mv = 0.f;
  if(sel){
    int fp  = (int)__popcll(FMASK & ((1ULL<<lane)-1ULL));
    int ord = 37*S2 + fp;
    if(ord < NUMBITS){
      mv = 1.f;
      double rnd = rint(coef);                  // round half-to-even == jnp.round
      int lsb = ((int)fabs(rnd)) & 1;
      int bit = secret[(size_t)bb*NUMBITS + ord];
      if(lsb != bit) coef += ((coef>=0.0)?1.0:-1.0)*(2.0*(double)bit-1.0)*0.5;
    }
  }
  out[(size_t)STEGO_N + (size_t)bi*64 + lane] = mv;
  // inv stage1: T2[r][v] = sum_u D[u][r]*M[u][v]
  double t2 = 0.0;
#pragma unroll
  for(int u=0;u<8;u++) t2 += DT.d[u][lr] * __shfl(coef, u*8+lc);
  // inv stage2: pix[r][k] = sum_q T2[r][q]*D[q][k]
  double px = 0.0;
#pragma unroll
  for(int qq=0;qq<8;qq++) px += __shfl(t2, lr*8+qq) * DT.d[qq][lc];
  po[(size_t)lr*HW + lc] = (float)px;
}

// ---------------- D0: zero the 512 bin counters (narrow, overlaps fills) ------
__global__ __launch_bounds__(512) void k_zero(unsigned* __restrict__ hist){
  hist[threadIdx.x] = 0u;
}

// ---------------- D1: copy + map-zero + variance + bucketed scatter ----------
__global__ __launch_bounds__(256) void k_stats(const float* __restrict__ cover,
    float* __restrict__ out, double* __restrict__ var,
    unsigned* __restrict__ hist, ull* __restrict__ bucket){
  int tid = threadIdx.x;
  int i = blockIdx.x*256 + tid;             // block id over (b,c,n,m)
  int m = i & 63, n = (i>>6)&63, bc = i>>12;
  const float* p  = cover + ((size_t)bc*HW + (size_t)n*8)*HW + (size_t)m*8;
  float*       po = out   + ((size_t)bc*HW + (size_t)n*8)*HW + (size_t)m*8;
  double s1=0.0, s2=0.0;
#pragma unroll
  for(int r=0;r<8;r++){
    const float4* q = (const float4*)(p + (size_t)r*HW);
    float4 a = q[0], b = q[1];
    float4* w = (float4*)(po + (size_t)r*HW);
    w[0]=a; w[1]=b;
    double x;
    x=(double)a.x; s1+=x; s2+=x*x;
    x=(double)a.y; s1+=x; s2+=x*x;
    x=(double)a.z; s1+=x; s2+=x*x;
    x=(double)a.w; s1+=x; s2+=x*x;
    x=(double)b.x; s1+=x; s2+=x*x;
    x=(double)b.y; s1+=x; s2+=x*x;
    x=(double)b.z; s1+=x; s2+=x*x;
    x=(double)b.w; s1+=x; s2+=x*x;
  }
  double mean = s1*(1.0/64.0);
  double v = s2*(1.0/64.0) - mean*mean;
  if(v < 0.0) v = 0.0;
  var[i] = v;
  // zero this block's embedding map (fixed up later for eligible blocks)
  float4 z = make_float4(0.f,0.f,0.f,0.f);
  float4* pm = (float4*)(out + (size_t)STEGO_N + (size_t)i*64);
#pragma unroll
  for(int j=0;j<16;j++) pm[j] = z;
  // histogram + bucket: counter doubles as bucket offset. Per-bin value SET is
  // deterministic (order isn't; downstream radix select is order-independent).
  int bn = binof(v);
  unsigned slot = atomicAdd(&hist[bn], 1u);
  if(slot < CAPB) bucket[(size_t)bn*CAPB + slot] = (ull)__double_as_longlong(v);
}

// ---------------- D2: hist scan -> bucket[b0] -> radix select -> embed -------
__global__ __launch_bounds__(1024) void k_embed(const float* __restrict__ cover,
    const int* __restrict__ secret, const double* __restrict__ var,
    const unsigned* __restrict__ hist, const ull* __restrict__ bucket,
    float* __restrict__ out){
  __shared__ ull scand[CAPB];               // 32 KB
  __shared__ unsigned rhist[2048];          // 8 KB (radix rounds)
  __shared__ unsigned wsum[16];
  __shared__ int sdesc[3];                  // b0, Cb, K
  __shared__ int spick[2];
  __shared__ int queue[ELIG];
  __shared__ unsigned wcnt[16];
  int tid = threadIdx.x, g = blockIdx.x;
  int lane = tid & 63, wid = tid >> 6;

  // ---- A: scan the 512 final bin counts -> b0 (bin holding RANK0), Cb ----
  unsigned part = 0, incl = 0;
  if(tid < HISTB){
    part = hist[tid];
    incl = part;
#pragma unroll
    for(int off=1; off<64; off<<=1){
      unsigned t = __shfl_up(incl, off);
      if(lane >= off) incl += t;
    }
    if(lane==63) wsum[wid]=incl;
  }
  __syncthreads();
  if(tid < HISTB){
    unsigned wpre=0;
#pragma unroll
    for(int w=0;w<8;w++) if(w<wid) wpre += wsum[w];
    unsigned c = wpre + incl - part;        // exclusive prefix of bin 'tid'
    if((unsigned)RANK0 >= c && (unsigned)RANK0 < c+part){
      sdesc[0]=tid; sdesc[1]=(int)c;
      sdesc[2]=(part < (unsigned)CAPB) ? (int)part : CAPB;
    }
  }
  __syncthreads();
  int b0 = sdesc[0], Cb = sdesc[1], K = sdesc[2];

  // ---- B: load bucket[b0] (one contiguous ~K*8 B run) into LDS ----
  const ull* src = bucket + (size_t)b0*CAPB;
  for(int t=tid;t<K;t+=1024) scand[t]=src[t];
  __syncthreads();

  // ---- C: radix select rank (RANK0-Cb) among K candidates -> A bits ----
  int rk = RANK0 - Cb;
  const int sh[6] = {55,44,33,22,11,0};
  ull pref = 0ULL;
  for(int r=0;r<6;r++){
    for(int j=tid;j<2048;j+=1024) rhist[j]=0u;
    __syncthreads();
    for(int t=tid;t<K;t+=1024){
      ull x = scand[t];
      bool match = (r==0) || ((x>>sh[r-1]) == (pref>>sh[r-1]));
      if(match) atomicAdd(&rhist[(unsigned)((x>>sh[r]) & 2047ULL)], 1u);
    }
    __syncthreads();
    unsigned a0 = rhist[2*tid], a1 = rhist[2*tid+1], p2 = a0+a1;
    unsigned inc2 = p2;
#pragma unroll
    for(int off=1; off<64; off<<=1){
      unsigned t = __shfl_up(inc2, off);
      if(lane >= off) inc2 += t;
    }
    if(lane==63) wsum[wid]=inc2;
    __syncthreads();
    unsigned wpre=0;
#pragma unroll
    for(int w=0;w<16;w++) if(w<wid) wpre += wsum[w];
    inc2 += wpre;
    unsigned excl = inc2 - p2;
    if((unsigned)rk >= excl && (unsigned)rk < inc2){
      if((unsigned)rk < excl + a0){ spick[0]=2*tid;   spick[1]=(int)excl; }
      else                        { spick[0]=2*tid+1; spick[1]=(int)(excl+a0); }
    }
    __syncthreads();
    pref |= ((ull)spick[0]) << sh[r];
    rk   -= spick[1];
    __syncthreads();
  }
  double A = __longlong_as_double((long long)pref);  // sel <=> var > A

  // ---- D: chunk-0 ballot -> queue; distributed one-wave-per-block embed ----
  {
    int f = (var[tid] > A) ? 1 : 0;         // block id == tid (chunk 0)
    ull bal = __ballot(f);
    if(lane==0) wcnt[wid] = (unsigned)__popcll(bal);
    __syncthreads();
    int wpre=0, csum=0;
#pragma unroll
    for(int w=0;w<16;w++){
      int cc = (int)wcnt[w];
      if(w<wid) wpre += cc;
      csum += cc;
    }
    int P = wpre + (int)__popcll(bal & ((1ULL<<lane)-1ULL));
    if(f && P < ELIG) queue[P] = tid;
    __syncthreads();
    if(csum >= ELIG){
      // common path: first ELIG selected blocks all lie in chunk 0
      int W = g*16 + wid;                   // global wave id in [0,1536)
      if(W < ELIG) embed_one(cover, secret, out, queue[W], W, lane);
      return;
    }
  }

  // ---- rare fallback: WG0 alone runs the full chunked scan + 16-wave embed ----
  if(g != 0) return;
  __syncthreads();
  int total = 0;
  for(int chunk=0; chunk<96; chunk++){
    int ii = chunk*1024 + tid;
    int f = (var[ii] > A) ? 1 : 0;
    ull bal = __ballot(f);
    if(lane==0) wcnt[wid] = (unsigned)__popcll(bal);
    __syncthreads();
    int wpre=0, csum=0;
#pragma unroll
    for(int w=0;w<16;w++){
      int cc = (int)wcnt[w];
      if(w<wid) wpre += cc;
      csum += cc;
    }
    int P = total + wpre + (int)__popcll(bal & ((1ULL<<lane)-1ULL));
    if(f && P < ELIG) queue[P] = ii;
    total += csum;
    __syncthreads();
    if(total >= ELIG) break;
  }
  int nq = (total < ELIG) ? total : ELIG;
  for(int q = wid; q < nq; q += 16)
    embed_one(cover, secret, out, queue[q], q, lane);
}

// ---------------- host launch ----------------
extern "C" void kernel_launch(void* const* d_in, const int* in_sizes, int n_in,
                              void* d_out, int out_size, void* d_ws, size_t ws_size,
                              hipStream_t stream) {
  const float* cover  = (const float*)d_in[0];
  const int*   secret = (const int*)d_in[1];
  float* out = (float*)d_out;
  char*  ws  = (char*)d_ws;

  // ws layout (bytes)
  double*   var    = (double*)(ws);                // 98304*8      = 786432
  unsigned* hist   = (unsigned*)(ws + 786432);     // 512*4        -> 788480
  ull*      bucket = (ull*)(ws + 788480);          // 512*4096*8   -> 17565696 (~16.8 MB)

  k_zero <<<1,   512,  0, stream>>>(hist);
  k_stats<<<384, 256,  0, stream>>>(cover, out, var, hist, bucket);
  k_embed<<<NWGS,1024, 0, stream>>>(cover, secret, var, hist, bucket, out);
}

// Round 15
// 47.739 us; speedup vs baseline: 3.4677x; 3.4677x over previous
//
#include <hip/hip_runtime.h>

// ---------------- problem constants ----------------
#define NBLK   98304     // 8*3*64*64 total 8x8 blocks
#define NPB    12288     // blocks per batch (3*64*64)
#define HW     512
#define NUMBITS 4096
#define RANK0  29490     // floor(0.3*(NBLK-1)); sel <=> var > s[RANK0] (adjacent order stats)
#define STEGO_N 6291456  // 8*3*512*512
#define ELIG   111       // ceil(4096/37) blocks contain eligible coefficients
#define HISTB  512       // fixed bins over variance range [0, 0.25]
#define CAPB   4096      // per-bin bucket capacity (b0 population ~500, validated R14)
#define NWGS   96

typedef unsigned long long ull;

// ---------------- DCT matrix as compile-time constants ----------------
struct DTab { double d[8][8]; };

constexpr double CT_[9] = {
  1.0,
  0.98078528040323044913,
  0.92387953251128675613,
  0.83146961230254523708,
  0.70710678118654752440,
  0.55557023301960222474,
  0.38268343236508977173,
  0.19509032201612826785,
  0.0
};
constexpr double cospi16(int m){           // cos(pi*m/16), m >= 0
  int r = m % 32;
  return (r<=8) ? CT_[r] : (r<=16) ? -CT_[16-r] : (r<=24) ? -CT_[r-16] : CT_[32-r];
}
constexpr DTab make_dtab(){
  DTab t{};
  for(int k=0;k<8;k++) for(int n=0;n<8;n++){
    double s = (k==0) ? 0.35355339059327376220 : 0.5; // sqrt(1/8), sqrt(2/8)
    t.d[k][n] = s * cospi16((2*n+1)*k);
  }
  return t;
}
constexpr DTab DT = make_dtab();

constexpr ull make_fmask(){ // bit u*8+v set iff 3 <= u+v <= 8
  ull m = 0;
  for(int u=0;u<8;u++) for(int v=0;v<8;v++){
    int s=u+v; if(s>=3 && s<=8) m |= (1ULL << (u*8+v));
  }
  return m;
}
constexpr ull FMASK = make_fmask();  // 37 bits set

__device__ __forceinline__ int binof(double v){
  int b = (int)(v * 2048.0);                // HISTB/0.25 — fixed, deterministic
  if(b > HISTB-1) b = HISTB-1;
  return b;                                 // v >= 0 always
}

// one WAVE embeds one block (global selected-rank S2); lane l owns coeff (l>>3,l&7)
__device__ __forceinline__ void embed_one(const float* __restrict__ cover,
    const int* __restrict__ secret, float* __restrict__ out, int bi, int S2, int lane){
  int lr = lane>>3, lc = lane&7;
  int m = bi & 63, n = (bi>>6)&63, bc = bi>>12, bb = bi / NPB;
  const float* p  = cover + ((size_t)bc*HW + (size_t)n*8)*HW + (size_t)m*8;
  float*       po = out   + ((size_t)bc*HW + (size_t)n*8)*HW + (size_t)m*8;
  double x = (double)p[(size_t)lr*HW + lc];     // X[lr][lc]
  // stage1: T1[r][v] = sum_j X[r][j]*D[v][j]
  double t1 = 0.0;
#pragma unroll
  for(int j=0;j<8;j++) t1 += __shfl(x, lr*8+j) * DT.d[lc][j];
  // stage2: C[u][v] = sum_k D[u][k]*T1[k][v]
  double coef = 0.0;
#pragma unroll
  for(int k=0;k<8;k++) coef += DT.d[lr][k] * __shfl(t1, k*8+lc);
  // embedding
  bool sel = (FMASK>>lane)&1ULL;
  float mv = 0.f;
  if(sel){
    int fp  = (int)__popcll(FMASK & ((1ULL<<lane)-1ULL));
    int ord = 37*S2 + fp;
    if(ord < NUMBITS){
      mv = 1.f;
      double rnd = rint(coef);                  // round half-to-even == jnp.round
      int lsb = ((int)fabs(rnd)) & 1;
      int bit = secret[(size_t)bb*NUMBITS + ord];
      if(lsb != bit) coef += ((coef>=0.0)?1.0:-1.0)*(2.0*(double)bit-1.0)*0.5;
    }
  }
  out[(size_t)STEGO_N + (size_t)bi*64 + lane] = mv;
  // inv stage1: T2[r][v] = sum_u D[u][r]*M[u][v]
  double t2 = 0.0;
#pragma unroll
  for(int u=0;u<8;u++) t2 += DT.d[u][lr] * __shfl(coef, u*8+lc);
  // inv stage2: pix[r][k] = sum_q T2[r][q]*D[q][k]
  double px = 0.0;
#pragma unroll
  for(int qq=0;qq<8;qq++) px += __shfl(t2, lr*8+qq) * DT.d[qq][lc];
  po[(size_t)lr*HW + lc] = (float)px;
}

// ---------------- D0: zero the 512 bin counters ----------------
__global__ __launch_bounds__(512) void k_zero(unsigned* __restrict__ hist){
  hist[threadIdx.x] = 0u;
}

// ---------------- D1: copy + map-zero + variance + two-level bucket scatter ----
__global__ __launch_bounds__(256) void k_stats(const float* __restrict__ cover,
    float* __restrict__ out, double* __restrict__ var,
    unsigned* __restrict__ hist, ull* __restrict__ bucket){
  __shared__ unsigned h [HISTB];            // pass-1 LDS counts
  __shared__ unsigned h2[HISTB];            // pass-2 local slots
  __shared__ unsigned gb[HISTB];            // reserved global base per bin
  int tid = threadIdx.x;
  int i = blockIdx.x*256 + tid;             // block id over (b,c,n,m)
  for(int j=tid;j<HISTB;j+=256){ h[j]=0u; h2[j]=0u; }
  int m = i & 63, n = (i>>6)&63, bc = i>>12;
  const float* p  = cover + ((size_t)bc*HW + (size_t)n*8)*HW + (size_t)m*8;
  float*       po = out   + ((size_t)bc*HW + (size_t)n*8)*HW + (size_t)m*8;
  double s1=0.0, s2=0.0;
#pragma unroll
  for(int r=0;r<8;r++){
    const float4* q = (const float4*)(p + (size_t)r*HW);
    float4 a = q[0], b = q[1];
    float4* w = (float4*)(po + (size_t)r*HW);
    w[0]=a; w[1]=b;
    double x;
    x=(double)a.x; s1+=x; s2+=x*x;
    x=(double)a.y; s1+=x; s2+=x*x;
    x=(double)a.z; s1+=x; s2+=x*x;
    x=(double)a.w; s1+=x; s2+=x*x;
    x=(double)b.x; s1+=x; s2+=x*x;
    x=(double)b.y; s1+=x; s2+=x*x;
    x=(double)b.z; s1+=x; s2+=x*x;
    x=(double)b.w; s1+=x; s2+=x*x;
  }
  double mean = s1*(1.0/64.0);
  double v = s2*(1.0/64.0) - mean*mean;
  if(v < 0.0) v = 0.0;
  var[i] = v;
  // zero this block's embedding map (fixed up later for eligible blocks)
  float4 z = make_float4(0.f,0.f,0.f,0.f);
  float4* pm = (float4*)(out + (size_t)STEGO_N + (size_t)i*64);
#pragma unroll
  for(int j=0;j<16;j++) pm[j] = z;
  // pass 1: LDS histogram (cheap, proven R12/R13)
  __syncthreads();
  int bn = binof(v);
  atomicAdd(&h[bn], 1u);
  __syncthreads();
  // range reservation: ONE global RMW per (WG, nonempty bin); chain <= 384/bin
  for(int j=tid;j<HISTB;j+=256){
    unsigned c = h[j];
    gb[j] = c ? atomicAdd(&hist[j], c) : 0u;
  }
  __syncthreads();
  // pass 2: local slot + plain store into reserved range
  unsigned slot = atomicAdd(&h2[bn], 1u);
  unsigned off  = gb[bn] + slot;
  if(off < CAPB) bucket[(size_t)bn*CAPB + off] = (ull)__double_as_longlong(v);
}

// ---------------- D2: hist scan -> bucket[b0] -> radix select -> embed -------
__global__ __launch_bounds__(1024) void k_embed(const float* __restrict__ cover,
    const int* __restrict__ secret, const double* __restrict__ var,
    const unsigned* __restrict__ hist, const ull* __restrict__ bucket,
    float* __restrict__ out){
  __shared__ ull scand[CAPB];               // 32 KB
  __shared__ unsigned rhist[2048];          // 8 KB (radix rounds)
  __shared__ unsigned wsum[16];
  __shared__ int sdesc[3];                  // b0, Cb, K
  __shared__ int spick[2];
  __shared__ int queue[ELIG];
  __shared__ unsigned wcnt[16];
  int tid = threadIdx.x, g = blockIdx.x;
  int lane = tid & 63, wid = tid >> 6;

  // ---- A: scan the 512 final bin counts -> b0 (bin holding RANK0), Cb ----
  unsigned part = 0, incl = 0;
  if(tid < HISTB){
    part = hist[tid];
    incl = part;
#pragma unroll
    for(int off=1; off<64; off<<=1){
      unsigned t = __shfl_up(incl, off);
      if(lane >= off) incl += t;
    }
    if(lane==63) wsum[wid]=incl;
  }
  __syncthreads();
  if(tid < HISTB){
    unsigned wpre=0;
#pragma unroll
    for(int w=0;w<8;w++) if(w<wid) wpre += wsum[w];
    unsigned c = wpre + incl - part;        // exclusive prefix of bin 'tid'
    if((unsigned)RANK0 >= c && (unsigned)RANK0 < c+part){
      sdesc[0]=tid; sdesc[1]=(int)c;
      sdesc[2]=(part < (unsigned)CAPB) ? (int)part : CAPB;
    }
  }
  __syncthreads();
  int b0 = sdesc[0], Cb = sdesc[1], K = sdesc[2];

  // ---- B: load bucket[b0] (one contiguous ~K*8 B run) into LDS ----
  const ull* src = bucket + (size_t)b0*CAPB;
  for(int t=tid;t<K;t+=1024) scand[t]=src[t];
  __syncthreads();

  // ---- C: radix select rank (RANK0-Cb) among K candidates -> A bits ----
  int rk = RANK0 - Cb;
  const int sh[6] = {55,44,33,22,11,0};
  ull pref = 0ULL;
  for(int r=0;r<6;r++){
    for(int j=tid;j<2048;j+=1024) rhist[j]=0u;
    __syncthreads();
    for(int t=tid;t<K;t+=1024){
      ull x = scand[t];
      bool match = (r==0) || ((x>>sh[r-1]) == (pref>>sh[r-1]));
      if(match) atomicAdd(&rhist[(unsigned)((x>>sh[r]) & 2047ULL)], 1u);
    }
    __syncthreads();
    unsigned a0 = rhist[2*tid], a1 = rhist[2*tid+1], p2 = a0+a1;
    unsigned inc2 = p2;
#pragma unroll
    for(int off=1; off<64; off<<=1){
      unsigned t = __shfl_up(inc2, off);
      if(lane >= off) inc2 += t;
    }
    if(lane==63) wsum[wid]=inc2;
    __syncthreads();
    unsigned wpre=0;
#pragma unroll
    for(int w=0;w<16;w++) if(w<wid) wpre += wsum[w];
    inc2 += wpre;
    unsigned excl = inc2 - p2;
    if((unsigned)rk >= excl && (unsigned)rk < inc2){
      if((unsigned)rk < excl + a0){ spick[0]=2*tid;   spick[1]=(int)excl; }
      else                        { spick[0]=2*tid+1; spick[1]=(int)(excl+a0); }
    }
    __syncthreads();
    pref |= ((ull)spick[0]) << sh[r];
    rk   -= spick[1];
    __syncthreads();
  }
  double A = __longlong_as_double((long long)pref);  // sel <=> var > A

  // ---- D: chunk-0 ballot -> queue; distributed one-wave-per-block embed ----
  {
    int f = (var[tid] > A) ? 1 : 0;         // block id == tid (chunk 0)
    ull bal = __ballot(f);
    if(lane==0) wcnt[wid] = (unsigned)__popcll(bal);
    __syncthreads();
    int wpre=0, csum=0;
#pragma unroll
    for(int w=0;w<16;w++){
      int cc = (int)wcnt[w];
      if(w<wid) wpre += cc;
      csum += cc;
    }
    int P = wpre + (int)__popcll(bal & ((1ULL<<lane)-1ULL));
    if(f && P < ELIG) queue[P] = tid;
    __syncthreads();
    if(csum >= ELIG){
      // common path: first ELIG selected blocks all lie in chunk 0
      int W = g*16 + wid;                   // global wave id in [0,1536)
      if(W < ELIG) embed_one(cover, secret, out, queue[W], W, lane);
      return;
    }
  }

  // ---- rare fallback: WG0 alone runs the full chunked scan + 16-wave embed ----
  if(g != 0) return;
  __syncthreads();
  int total = 0;
  for(int chunk=0; chunk<96; chunk++){
    int ii = chunk*1024 + tid;
    int f = (var[ii] > A) ? 1 : 0;
    ull bal = __ballot(f);
    if(lane==0) wcnt[wid] = (unsigned)__popcll(bal);
    __syncthreads();
    int wpre=0, csum=0;
#pragma unroll
    for(int w=0;w<16;w++){
      int cc = (int)wcnt[w];
      if(w<wid) wpre += cc;
      csum += cc;
    }
    int P = total + wpre + (int)__popcll(bal & ((1ULL<<lane)-1ULL));
    if(f && P < ELIG) queue[P] = ii;
    total += csum;
    __syncthreads();
    if(total >= ELIG) break;
  }
  int nq = (total < ELIG) ? total : ELIG;
  for(int q = wid; q < nq; q += 16)
    embed_one(cover, secret, out, queue[q], q, lane);
}

// ---------------- host launch ----------------
extern "C" void kernel_launch(void* const* d_in, const int* in_sizes, int n_in,
                              void* d_out, int out_size, void* d_ws, size_t ws_size,
                              hipStream_t stream) {
  const float* cover  = (const float*)d_in[0];
  const int*   secret = (const int*)d_in[1];
  float* out = (float*)d_out;
  char*  ws  = (char*)d_ws;

  // ws layout (bytes)
  double*   var    = (double*)(ws);                // 98304*8      = 786432
  unsigned* hist   = (unsigned*)(ws + 786432);     // 512*4        -> 788480
  ull*      bucket = (ull*)(ws + 788480);          // 512*4096*8   -> ~17.6 MB

  k_zero <<<1,   512,  0, stream>>>(hist);
  k_stats<<<384, 256,  0, stream>>>(cover, out, var, hist, bucket);
  k_embed<<<NWGS,1024, 0, stream>>>(cover, secret, var, hist, bucket, out);
}